// Round 1
// baseline (325.818 us; speedup 1.0000x reference)
//
#include <hip/hip_runtime.h>

// z = x @ W.T - b  (65536x512 @ (256x512)^T), then per-row projection onto
// {y : |1^T y| <= S, ||y||^2 <= R2}. Projection is affine per row: y = a*z + b0,
// so the GEMM epilogue only needs per-row (t, zz) reductions.
//
// bf16 MFMA GEMM (tolerance 9.3e-4 >> bf16 error * projection scale ~2e-5).
// BM=64, BN=256 (full N per block), BK=64, 256 threads / 4 waves,
// each wave = 64x64 via 4x4 grid of 16x16x32 MFMA.

typedef __bf16 bf16x8 __attribute__((ext_vector_type(8)));
typedef float f32x4 __attribute__((ext_vector_type(4)));

#define BM 64
#define BN 256
#define BK 64
#define LDK 72   // bf16 elems/row: BK + 8 pad -> 144 B rows, 16B-aligned, breaks bank alias
#define THREADS 256

__device__ __forceinline__ unsigned short f2bf(float f) {
    unsigned u = __builtin_bit_cast(unsigned, f);
    u += 0x7fffu + ((u >> 16) & 1u);     // round-to-nearest-even
    return (unsigned short)(u >> 16);
}

__global__ __launch_bounds__(THREADS, 3)
void proj_gemm_kernel(const float* __restrict__ x,
                      const float* __restrict__ W,
                      const float* __restrict__ b,
                      float* __restrict__ out) {
    __shared__ alignas(16) unsigned short Abuf[BM * LDK];   //  9216 B
    __shared__ alignas(16) unsigned short Bbuf[BN * LDK];   // 36864 B

    const int tid  = threadIdx.x;
    const int lane = tid & 63;
    const int wn   = tid >> 6;        // wave id 0..3 = N-tile (64 cols each)
    const int ln   = lane & 15;
    const int quad = lane >> 4;
    const int m0   = blockIdx.x * BM;

    // staging coords: 16 float4 per row, 16 threads per row
    const int arow = tid >> 4;        // 0..15
    const int kq   = tid & 15;        // float4 index within row

    const float* xbase = x + (long)(m0 + arow) * 512 + kq * 4;
    const float* wbase = W + (long)arow * 512 + kq * 4;

    f32x4 acc[4][4];
    #pragma unroll
    for (int mi = 0; mi < 4; ++mi)
        #pragma unroll
        for (int ni = 0; ni < 4; ++ni)
            acc[mi][ni] = (f32x4){0.f, 0.f, 0.f, 0.f};

    for (int kt = 0; kt < 8; ++kt) {
        const int k0 = kt * BK;
        __syncthreads();
        // stage A (x tile): 64 rows x 16 float4
        #pragma unroll
        for (int p = 0; p < 4; ++p) {
            const int row = arow + p * 16;
            float4 v = *(const float4*)(xbase + (long)p * 16 * 512 + k0);
            ushort4 h;
            h.x = f2bf(v.x); h.y = f2bf(v.y); h.z = f2bf(v.z); h.w = f2bf(v.w);
            *(ushort4*)&Abuf[row * LDK + kq * 4] = h;
        }
        // stage B (W tile): 256 rows x 16 float4
        #pragma unroll
        for (int p = 0; p < 16; ++p) {
            const int row = arow + p * 16;
            float4 v = *(const float4*)(wbase + (long)p * 16 * 512 + k0);
            ushort4 h;
            h.x = f2bf(v.x); h.y = f2bf(v.y); h.z = f2bf(v.z); h.w = f2bf(v.w);
            *(ushort4*)&Bbuf[row * LDK + kq * 4] = h;
        }
        __syncthreads();
        #pragma unroll
        for (int ks = 0; ks < 2; ++ks) {
            bf16x8 bf[4];
            #pragma unroll
            for (int ni = 0; ni < 4; ++ni)
                bf[ni] = *(const bf16x8*)&Bbuf[(wn*64 + ni*16 + ln) * LDK + ks*32 + quad*8];
            #pragma unroll
            for (int mi = 0; mi < 4; ++mi) {
                bf16x8 af = *(const bf16x8*)&Abuf[(mi*16 + ln) * LDK + ks*32 + quad*8];
                #pragma unroll
                for (int ni = 0; ni < 4; ++ni)
                    acc[mi][ni] = __builtin_amdgcn_mfma_f32_16x16x32_bf16(
                        af, bf[ni], acc[mi][ni], 0, 0, 0);
            }
        }
    }

    // subtract bias (must happen before row-sum reductions)
    float bb[4];
    #pragma unroll
    for (int ni = 0; ni < 4; ++ni) bb[ni] = b[wn*64 + ni*16 + ln];
    #pragma unroll
    for (int mi = 0; mi < 4; ++mi)
        #pragma unroll
        for (int ni = 0; ni < 4; ++ni)
            #pragma unroll
            for (int r = 0; r < 4; ++r)
                acc[mi][ni][r] -= bb[ni];

    __syncthreads();                  // all waves done reading Abuf/Bbuf
    float* P  = (float*)Abuf;         // per-row partials: 64 rows x (4 waves x {t,zz})
    float* AB = P + 64 * 8;           // per-row alpha/beta

    // per-row partial sums over this wave's 64 cols.
    // C/D layout: col = ln, row(within 16) = quad*4 + r.
    #pragma unroll
    for (int mi = 0; mi < 4; ++mi) {
        #pragma unroll
        for (int r = 0; r < 4; ++r) {
            float s1 = 0.f, s2 = 0.f;
            #pragma unroll
            for (int ni = 0; ni < 4; ++ni) {
                float v = acc[mi][ni][r];
                s1 += v; s2 += v * v;
            }
            #pragma unroll
            for (int off = 1; off < 16; off <<= 1) {
                s1 += __shfl_xor(s1, off, 64);
                s2 += __shfl_xor(s2, off, 64);
            }
            if (ln == 0) {
                int row = mi*16 + quad*4 + r;
                P[row*8 + wn*2 + 0] = s1;
                P[row*8 + wn*2 + 1] = s2;
            }
        }
    }
    __syncthreads();

    // one thread per row: combine partials, KKT case analysis -> (alpha, beta)
    if (tid < 64) {
        int row = tid;
        float t  = P[row*8+0] + P[row*8+2] + P[row*8+4] + P[row*8+6];
        float zz = P[row*8+1] + P[row*8+3] + P[row*8+5] + P[row*8+7];
        const float S = 0.1f, R2 = 0.02f, nf = 256.f, inv_n = 1.f / 256.f;
        float tc    = fminf(fmaxf(t, -S), S);
        float beta1 = (tc - t) * inv_n;
        float ny1   = zz + 2.f*beta1*t + nf*beta1*beta1;   // ||y1||^2 closed form
        float alpha, beta;
        if (ny1 <= R2) {
            alpha = 1.f; beta = beta1;
        } else {
            float znorm = sqrtf(fmaxf(zz, 1e-12f));
            float scale = fminf(1.f, 0.14142135623730951f / znorm);  // sqrt(R2)
            if (fabsf(t) * scale <= S) {
                alpha = scale; beta = 0.f;
            } else {
                float denom = fmaxf(nf*zz - t*t, 1e-12f);
                float c  = sqrtf(5.11f / denom);            // n*R2 - S*S = 5.11
                float sp = (t > 0.f) ? S : ((t < 0.f) ? -S : 0.f);
                alpha = c; beta = (sp - c*t) * inv_n;
            }
        }
        AB[row*2+0] = alpha;
        AB[row*2+1] = beta;
    }
    __syncthreads();

    // apply y = alpha*z + beta and store
    #pragma unroll
    for (int mi = 0; mi < 4; ++mi) {
        #pragma unroll
        for (int r = 0; r < 4; ++r) {
            int row = mi*16 + quad*4 + r;
            float alpha = AB[row*2+0];
            float beta  = AB[row*2+1];
            float* orow = out + (long)(m0 + row) * 256 + wn*64 + ln;
            #pragma unroll
            for (int ni = 0; ni < 4; ++ni)
                orow[ni*16] = alpha * acc[mi][ni][r] + beta;
        }
    }
}

extern "C" void kernel_launch(void* const* d_in, const int* in_sizes, int n_in,
                              void* d_out, int out_size, void* d_ws, size_t ws_size,
                              hipStream_t stream) {
    const float* x = (const float*)d_in[0];   // [B, 512]
    const float* W = (const float*)d_in[1];   // [256, 512]
    const float* b = (const float*)d_in[2];   // [256]
    float* out = (float*)d_out;               // [B, 256]

    const int Dout = in_sizes[2];             // 256
    const int Din  = in_sizes[1] / Dout;      // 512
    const int Btot = in_sizes[0] / Din;       // 65536
    const int grid = Btot / BM;               // 1024

    proj_gemm_kernel<<<grid, THREADS, 0, stream>>>(x, W, b, out);
}

// Round 2
// 219.856 us; speedup vs baseline: 1.4820x; 1.4820x over previous
//
#include <hip/hip_runtime.h>

// z = x @ W.T - b (65536x512 @ (256x512)^T) -> row-wise projection onto
// {y: |1^T y|<=S, ||y||^2<=R2}. Projection is affine per row (y = a*z + b0),
// fused into the GEMM epilogue via per-row (t, zz) reductions.
//
// R2 restructure vs R1 (latency-bound, all pipes <10%):
//  - W pre-converted to bf16 ONCE (kernel 1) -> GEMM stages B via
//    global_load_lds width=16 (no VGPR round trip, no per-tile conversion).
//  - B LDS layout XOR-swizzled by row (global_load_lds forbids padding);
//    MFMA B-frag reads land 2-way bank aliased (free) instead of 16-way.
//  - BM=128, 512 threads, grid=512 -> all blocks resident (2/CU, 16 waves/CU).

typedef __bf16 bf16x8 __attribute__((ext_vector_type(8)));
typedef float f32x4 __attribute__((ext_vector_type(4)));

#define BM 128
#define BN 256
#define BK 64
#define LDA 72     // A-tile row pitch (bf16): 144B rows, 16B-aligned, banks spread
#define THREADS 512

__device__ __forceinline__ unsigned short f2bf(float f) {
    unsigned u = __builtin_bit_cast(unsigned, f);
    u += 0x7fffu + ((u >> 16) & 1u);     // RNE
    return (unsigned short)(u >> 16);
}

// one-time: W fp32 [256][512] -> bf16 row-major in workspace
__global__ void wconv_kernel(const float* __restrict__ W,
                             unsigned short* __restrict__ Wb) {
    int i = (blockIdx.x * 256 + threadIdx.x) * 4;
    float4 v = *(const float4*)(W + i);
    ushort4 h;
    h.x = f2bf(v.x); h.y = f2bf(v.y); h.z = f2bf(v.z); h.w = f2bf(v.w);
    *(ushort4*)(Wb + i) = h;
}

__global__ __launch_bounds__(THREADS, 4)
void proj_gemm_kernel(const float* __restrict__ x,
                      const unsigned short* __restrict__ Wb,
                      const float* __restrict__ b,
                      float* __restrict__ out) {
    __shared__ alignas(16) unsigned short Abuf[BM * LDA];   // 18432 B
    __shared__ alignas(16) unsigned short Bbuf[BN * BK];    // 32768 B, chunk-swizzled

    const int tid  = threadIdx.x;
    const int lane = tid & 63;
    const int wv   = tid >> 6;        // 0..7
    const int wm   = wv >> 2;         // m-half (0..1)
    const int wn   = wv & 3;          // n-quarter (0..3)
    const int ln   = lane & 15;
    const int quad = lane >> 4;
    const int m0   = blockIdx.x * BM;

    // A staging coords: 128 rows x 16 float4-chunks, 512 threads -> 4 each
    const int arow = tid >> 4;        // 0..31
    const int kq   = tid & 15;
    const float* xbase = x + (long)(m0 + arow) * 512 + kq * 4;

    // B staging via global_load_lds: issue j covers flat 16B-chunks
    // f = (wv*4+j)*64 + lane; r = f>>3; swizzled col-chunk cg = (lane&7)^(lane>>3).
    // Source row-group of 8 lanes covers one full 128B segment (perfect coalescing).
    const int b_r0 = wv * 32 + (lane >> 3);          // row for j=0; +8 per j
    const int b_cg = (lane & 7) ^ (lane >> 3);       // 16B chunk within row

    f32x4 acc[4][4];
    #pragma unroll
    for (int mi = 0; mi < 4; ++mi)
        #pragma unroll
        for (int ni = 0; ni < 4; ++ni)
            acc[mi][ni] = (f32x4){0.f, 0.f, 0.f, 0.f};

    for (int kt = 0; kt < 8; ++kt) {
        const int k0 = kt * BK;
        __syncthreads();
        // stage B: 4 async 16B/lane transfers per wave, no VGPR round-trip
        #pragma unroll
        for (int j = 0; j < 4; ++j) {
            const unsigned short* src =
                Wb + (long)(b_r0 + j * 8) * 512 + k0 + b_cg * 8;
            __builtin_amdgcn_global_load_lds(
                (const __attribute__((address_space(1))) void*)src,
                (__attribute__((address_space(3))) void*)(unsigned long)(unsigned int)
                    (unsigned long)(uintptr_t)&Bbuf[(wv * 4 + j) * 512],
                16, 0, 0);
        }
        // stage A: fp32 load -> bf16 -> LDS (padded pitch)
        #pragma unroll
        for (int p = 0; p < 4; ++p) {
            const int row = arow + p * 32;
            float4 v = *(const float4*)(xbase + (long)p * 32 * 512 + k0);
            ushort4 h;
            h.x = f2bf(v.x); h.y = f2bf(v.y); h.z = f2bf(v.z); h.w = f2bf(v.w);
            *(ushort4*)&Abuf[row * LDA + kq * 4] = h;
        }
        __syncthreads();
        #pragma unroll
        for (int ks = 0; ks < 2; ++ks) {
            bf16x8 bf[4];
            #pragma unroll
            for (int ni = 0; ni < 4; ++ni) {
                const int r  = wn * 64 + ni * 16 + ln;
                const int cc = (ks * 4 + quad) ^ (ln & 7);   // un-swizzle
                bf[ni] = *(const bf16x8*)&Bbuf[r * 64 + cc * 8];
            }
            #pragma unroll
            for (int mi = 0; mi < 4; ++mi) {
                const int row = wm * 64 + mi * 16 + ln;
                bf16x8 af = *(const bf16x8*)&Abuf[row * LDA + ks * 32 + quad * 8];
                #pragma unroll
                for (int ni = 0; ni < 4; ++ni)
                    acc[mi][ni] = __builtin_amdgcn_mfma_f32_16x16x32_bf16(
                        af, bf[ni], acc[mi][ni], 0, 0, 0);
            }
        }
    }

    // bias before row reductions
    float bb[4];
    #pragma unroll
    for (int ni = 0; ni < 4; ++ni) bb[ni] = b[wn * 64 + ni * 16 + ln];
    #pragma unroll
    for (int mi = 0; mi < 4; ++mi)
        #pragma unroll
        for (int ni = 0; ni < 4; ++ni)
            #pragma unroll
            for (int r = 0; r < 4; ++r)
                acc[mi][ni][r] -= bb[ni];

    __syncthreads();
    float* P  = (float*)Abuf;         // 128 rows x {4 waves x (t,zz)} = 4 KB
    float* AB = P + 128 * 8;          // 128 x (alpha,beta)

    // per-row partials over this wave's 64 cols (cols indexed by ni,ln)
    #pragma unroll
    for (int mi = 0; mi < 4; ++mi) {
        #pragma unroll
        for (int r = 0; r < 4; ++r) {
            float s1 = 0.f, s2 = 0.f;
            #pragma unroll
            for (int ni = 0; ni < 4; ++ni) {
                float v = acc[mi][ni][r];
                s1 += v; s2 += v * v;
            }
            #pragma unroll
            for (int off = 1; off < 16; off <<= 1) {
                s1 += __shfl_xor(s1, off, 64);
                s2 += __shfl_xor(s2, off, 64);
            }
            if (ln == 0) {
                int row = wm * 64 + mi * 16 + quad * 4 + r;
                P[row * 8 + wn * 2 + 0] = s1;
                P[row * 8 + wn * 2 + 1] = s2;
            }
        }
    }
    __syncthreads();

    // one thread per row: KKT case analysis -> (alpha, beta)
    if (tid < 128) {
        int row = tid;
        float t  = P[row*8+0] + P[row*8+2] + P[row*8+4] + P[row*8+6];
        float zz = P[row*8+1] + P[row*8+3] + P[row*8+5] + P[row*8+7];
        const float S = 0.1f, R2 = 0.02f, nf = 256.f, inv_n = 1.f / 256.f;
        float tc    = fminf(fmaxf(t, -S), S);
        float beta1 = (tc - t) * inv_n;
        float ny1   = zz + 2.f * beta1 * t + nf * beta1 * beta1;
        float alpha, beta;
        if (ny1 <= R2) {
            alpha = 1.f; beta = beta1;
        } else {
            float znorm = sqrtf(fmaxf(zz, 1e-12f));
            float scale = fminf(1.f, 0.14142135623730951f / znorm);
            if (fabsf(t) * scale <= S) {
                alpha = scale; beta = 0.f;
            } else {
                float denom = fmaxf(nf * zz - t * t, 1e-12f);
                float c  = sqrtf(5.11f / denom);             // n*R2 - S^2
                float sp = (t > 0.f) ? S : ((t < 0.f) ? -S : 0.f);
                alpha = c; beta = (sp - c * t) * inv_n;
            }
        }
        AB[row*2+0] = alpha;
        AB[row*2+1] = beta;
    }
    __syncthreads();

    // apply y = alpha*z + beta, store
    #pragma unroll
    for (int mi = 0; mi < 4; ++mi) {
        #pragma unroll
        for (int r = 0; r < 4; ++r) {
            int row = wm * 64 + mi * 16 + quad * 4 + r;
            float alpha = AB[row*2+0];
            float beta  = AB[row*2+1];
            float* orow = out + (long)(m0 + row) * 256 + wn * 64 + ln;
            #pragma unroll
            for (int ni = 0; ni < 4; ++ni)
                orow[ni*16] = alpha * acc[mi][ni][r] + beta;
        }
    }
}

extern "C" void kernel_launch(void* const* d_in, const int* in_sizes, int n_in,
                              void* d_out, int out_size, void* d_ws, size_t ws_size,
                              hipStream_t stream) {
    const float* x = (const float*)d_in[0];   // [65536, 512]
    const float* W = (const float*)d_in[1];   // [256, 512]
    const float* b = (const float*)d_in[2];   // [256]
    float* out = (float*)d_out;               // [65536, 256]
    unsigned short* Wb = (unsigned short*)d_ws; // 256KB bf16 W

    const int Dout = in_sizes[2];             // 256
    const int Din  = in_sizes[1] / Dout;      // 512
    const int Btot = in_sizes[0] / Din;       // 65536

    wconv_kernel<<<(Dout * Din) / (256 * 4), 256, 0, stream>>>(W, Wb);
    proj_gemm_kernel<<<Btot / BM, THREADS, 0, stream>>>(x, Wb, b, out);
}